// Round 12
// baseline (286.371 us; speedup 1.0000x reference)
//
#include <hip/hip_runtime.h>
#include <cstdint>
#include <cstddef>

#define NEG_SLOPE 0.2f
#define BN_EPS 1e-5f
#define BK_SHIFT 8          // 256 nodes per bucket
#define MAXBK 512           // supports N <= 131072
#define CHUNK 2048          // edges per binning block (small: parallel tail)
#define CAP 8192            // slots per bucket (mean fill 4352, +58 sigma)

typedef _Float16 half4 __attribute__((ext_vector_type(4)));

// ---------------------------------------------------------------------------
// K0: fold b1 + BN(eval) into per-channel scale/shift, zero bucket cursors.
// ---------------------------------------------------------------------------
__global__ void prep_kernel(const float* __restrict__ b1,
                            const float* __restrict__ bn_gamma,
                            const float* __restrict__ bn_beta,
                            const float* __restrict__ bn_mean,
                            const float* __restrict__ bn_var,
                            float* __restrict__ pre0,
                            float* __restrict__ pre1,
                            int* __restrict__ bucket_cursor) {
    int t = threadIdx.x;            // 512 threads
    if (t < 128) {
        float sc = rsqrtf(bn_var[t] + BN_EPS) * bn_gamma[t];
        pre0[t] = sc;
        pre1[t] = (b1[t] - bn_mean[t]) * sc + bn_beta[t];
    }
    if (t < MAXBK) bucket_cursor[t] = 0;
}

// ---------------------------------------------------------------------------
// K1: binning pass, standalone. CHUNK=2048 -> 832 blocks (3+/CU) so the
// per-block serial cost (3 passes + conflicted LDS atomics) parallelizes
// instead of forming a 208-block tail (R11's gemm_bin long pole).
// LDS histogram over 256-node buckets -> one reservation per (block,bucket)
// -> compact packed writes  word = (dst&255)<<24 | src   (needs N < 2^24).
// ---------------------------------------------------------------------------
__global__ void bin_kernel(const int* __restrict__ ei, int E, int N, int NBK,
                           int* __restrict__ bucket_cursor,
                           unsigned int* __restrict__ binned) {
    __shared__ int cnt[MAXBK];
    __shared__ int gstart[MAXBK];
    __shared__ int cur[MAXBK];
    int T = E + N;
    for (int b = threadIdx.x; b < NBK; b += 256) { cnt[b] = 0; cur[b] = 0; }
    __syncthreads();
    int base = blockIdx.x * CHUNK;
    for (int k = 0; k < CHUNK; k += 256) {
        int i = base + k + threadIdx.x;
        if (i < T) {
            int dst = (i < E) ? ei[E + i] : (i - E);
            atomicAdd(&cnt[dst >> BK_SHIFT], 1);
        }
    }
    __syncthreads();
    for (int b = threadIdx.x; b < NBK; b += 256) {
        int c = cnt[b];
        if (c) gstart[b] = atomicAdd(&bucket_cursor[b], c);
    }
    __syncthreads();
    for (int k = 0; k < CHUNK; k += 256) {
        int i = base + k + threadIdx.x;
        if (i < T) {
            int src, dst;
            if (i < E) { src = ei[i]; dst = ei[E + i]; }
            else       { src = i - E; dst = src; }
            int b = dst >> BK_SHIFT;
            int lp = gstart[b] + atomicAdd(&cur[b], 1);
            if (lp < CAP)       // overflow guard (statistically impossible)
                binned[(size_t)b * CAP + lp] =
                    (unsigned int)src | ((unsigned int)(dst & 255) << 24);
        }
    }
}

// ---------------------------------------------------------------------------
// K2 (fused): blockIdx < NBK -> csr finalize (depends on bin);
//             else           -> gemm1 (independent -> hides csr's latency).
// csr: per-bucket LDS count -> scan -> row_beg/row_end -> in-bucket scatter.
// gemm: h0[N,128] = x@W1 (fp16 store), fused as1/ad1 epilogue.
// ---------------------------------------------------------------------------
__global__ void csr_gemm_kernel(// csr args
                                const unsigned int* __restrict__ binned,
                                const int* __restrict__ bucket_cursor,
                                int* __restrict__ row_beg,
                                int* __restrict__ row_end,
                                int* __restrict__ csr_src,
                                int NBK,
                                // gemm args
                                const float* __restrict__ x,
                                const float* __restrict__ W1,
                                const float* __restrict__ att_s,
                                const float* __restrict__ att_d,
                                _Float16* __restrict__ h0,
                                float* __restrict__ as1,
                                float* __restrict__ ad1,
                                int N) {
    __shared__ int cnt[256];
    __shared__ int loc[256];
    __shared__ int cur[256];
    if (blockIdx.x < NBK) {
        int b = blockIdx.x;
        int tid = threadIdx.x;          // 256 threads
        int n0 = b << BK_SHIFT;
        int nr = N - n0; if (nr > 256) nr = 256;
        int tot = bucket_cursor[b];
        if (tot > CAP) tot = CAP;
        size_t base = (size_t)b * CAP;
        cnt[tid] = 0;
        __syncthreads();
        for (int j = tid; j < tot; j += 256) {
            atomicAdd(&cnt[binned[base + j] >> 24], 1);
        }
        __syncthreads();
        int v = cnt[tid];
        loc[tid] = v;
        __syncthreads();
        for (int off = 1; off < 256; off <<= 1) {
            int t = (tid >= off) ? loc[tid - off] : 0;
            __syncthreads();
            loc[tid] += t;
            __syncthreads();
        }
        int excl = loc[tid] - v;
        cur[tid] = excl;
        if (tid < nr) {
            row_beg[n0 + tid] = (int)base + excl;
            row_end[n0 + tid] = (int)base + excl + v;
        }
        __syncthreads();
        for (int j = tid; j < tot; j += 256) {
            unsigned int w = binned[base + j];
            int pos = atomicAdd(&cur[w >> 24], 1);
            csr_src[base + pos] = (int)(w & 0xFFFFFFu);
        }
        return;
    }
    // ----- gemm path: 4 nodes per thread (W1 reuse x4), fp16 h0 store
    int bid = blockIdx.x - NBK;
    int c = threadIdx.x & 127;
    int pair = __builtin_amdgcn_readfirstlane(threadIdx.x >> 7);
    int n0 = (bid * 2 + pair) * 4;
    if (n0 >= N) return;
    float acc[4] = {0.f, 0.f, 0.f, 0.f};
    const float* __restrict__ xr = x + (size_t)n0 * 64;
    int nn = N - n0; if (nn > 4) nn = 4;
    if (nn == 4) {
#pragma unroll
        for (int k = 0; k < 64; ++k) {
            float w = W1[k * 128 + c];
            acc[0] = fmaf(xr[k],       w, acc[0]);
            acc[1] = fmaf(xr[64 + k],  w, acc[1]);
            acc[2] = fmaf(xr[128 + k], w, acc[2]);
            acc[3] = fmaf(xr[192 + k], w, acc[3]);
        }
    } else {
        for (int i = 0; i < nn; ++i)
            for (int k = 0; k < 64; ++k)
                acc[i] = fmaf(xr[i * 64 + k], W1[k * 128 + c], acc[i]);
    }
    float asc = att_s[c], adc = att_d[c];
    int head = c >> 5;
#pragma unroll
    for (int i = 0; i < 4; ++i) {
        if (i >= nn) break;
        int n = n0 + i;
        h0[(size_t)n * 128 + c] = (_Float16)acc[i];
        float s = acc[i] * asc;
        float d = acc[i] * adc;
#pragma unroll
        for (int off = 16; off >= 1; off >>= 1) {
            s += __shfl_xor(s, off);
            d += __shfl_xor(d, off);
        }
        if ((threadIdx.x & 31) == 0) {
            as1[(size_t)n * 4 + head] = s;
            ad1[(size_t)n * 4 + head] = d;
        }
    }
}

// ---------------------------------------------------------------------------
// K3: layer-1 gather + finalize — the R5/R7-PROVEN body, unchanged.
// ONE WAVE per dst node (block 256 = 4 nodes); 2x32-lane edge-groups;
// half4 (8B dwordx2) h0 loads; redundant-but-overlappable exp per 8-lane
// head group; register accumulators; shfl combine; prefolded pre0/pre1.
// (R6 half8/16-lane, R9 two-phase LDS, R10 LDS-atomic variants all
// regressed — do not restructure this loop.)
// ---------------------------------------------------------------------------
__global__ void gather1_kernel(const int* __restrict__ row_beg,
                               const int* __restrict__ row_end,
                               const int* __restrict__ csr_src,
                               const half4* __restrict__ h0,
                               const float* __restrict__ as1,
                               const float* __restrict__ ad1,
                               const float* __restrict__ pre0,
                               const float* __restrict__ pre1,
                               const float* __restrict__ W2,
                               float* __restrict__ h2, int N) {
    int n = blockIdx.x * 4 + (threadIdx.x >> 6);
    if (n >= N) return;
    int lane = threadIdx.x & 63;
    int sub  = lane & 31;           // half4 index within the 128-ch row
    int grp  = lane >> 5;           // which edge of the pair
    int head = sub >> 3;            // channels 4*sub..4*sub+3 are in this head
    float ad = ad1[(size_t)n * 4 + head];
    int beg = row_beg[n];
    int end = row_end[n];
    float4 acc = make_float4(0.f, 0.f, 0.f, 0.f);
    float den = 0.f;
#pragma unroll 2
    for (int j = beg + grp; j < end; j += 2) {
        int src = csr_src[j];
        float as = as1[(size_t)src * 4 + head];
        float lg = as + ad;
        float l = fmaf(NEG_SLOPE, fminf(lg, 0.f), fmaxf(lg, 0.f));
        float w = __expf(l);
        half4 hv = h0[(size_t)src * 32 + sub];
        acc.x = fmaf(w, (float)hv.x, acc.x);
        acc.y = fmaf(w, (float)hv.y, acc.y);
        acc.z = fmaf(w, (float)hv.z, acc.z);
        acc.w = fmaf(w, (float)hv.w, acc.w);
        den += w;
    }
    acc.x += __shfl_xor(acc.x, 32);
    acc.y += __shfl_xor(acc.y, 32);
    acc.z += __shfl_xor(acc.z, 32);
    acc.w += __shfl_xor(acc.w, 32);
    den   += __shfl_xor(den, 32);
    float inv = 1.f / (den + 1e-16f);
    int c = sub * 4;
    float v0 = fmaf(acc.x * inv, pre0[c],     pre1[c]);
    float v1 = fmaf(acc.y * inv, pre0[c + 1], pre1[c + 1]);
    float v2 = fmaf(acc.z * inv, pre0[c + 2], pre1[c + 2]);
    float v3 = fmaf(acc.w * inv, pre0[c + 3], pre1[c + 3]);
    v0 = v0 > 0.f ? v0 : expm1f(v0);
    v1 = v1 > 0.f ? v1 : expm1f(v1);
    v2 = v2 > 0.f ? v2 : expm1f(v2);
    v3 = v3 > 0.f ? v3 : expm1f(v3);
    float t = v0 * W2[c] + v1 * W2[c + 1] + v2 * W2[c + 2] + v3 * W2[c + 3];
#pragma unroll
    for (int off = 16; off >= 1; off >>= 1) t += __shfl_xor(t, off);
    if (lane == 0) h2[n] = t;
}

// ---------------------------------------------------------------------------
// K4: layer-2 gather (R7-proven). 16-lane group per dst node
// (block 256 = 16 nodes); mean degree ~17 -> lanes ~fully utilized.
// ---------------------------------------------------------------------------
__global__ void gather2_kernel(const int* __restrict__ row_beg,
                               const int* __restrict__ row_end,
                               const int* __restrict__ csr_src,
                               const float* __restrict__ h2,
                               const float* __restrict__ att_s2,
                               const float* __restrict__ att_d2,
                               const float* __restrict__ b2,
                               float* __restrict__ out, int N) {
    int n = blockIdx.x * 16 + (threadIdx.x >> 4);
    if (n >= N) return;
    int lane = threadIdx.x & 15;
    int beg = row_beg[n];
    int end = row_end[n];
    float a_s = att_s2[0];
    float a_d = att_d2[0];
    float hd = h2[n];
    float num = 0.f, den = 0.f;
    for (int j = beg + lane; j < end; j += 16) {
        int src = csr_src[j];
        float hs = h2[src];
        float lg = hs * a_s + hd * a_d;
        float l = fmaf(NEG_SLOPE, fminf(lg, 0.f), fmaxf(lg, 0.f));
        float w = __expf(l);
        num += w * hs;
        den += w;
    }
#pragma unroll
    for (int off = 8; off >= 1; off >>= 1) {
        num += __shfl_xor(num, off);
        den += __shfl_xor(den, off);
    }
    if (lane == 0) out[n] = num / (den + 1e-16f) + b2[0];
}

extern "C" void kernel_launch(void* const* d_in, const int* in_sizes, int n_in,
                              void* d_out, int out_size, void* d_ws, size_t ws_size,
                              hipStream_t stream) {
    const float* x     = (const float*)d_in[0];
    const int*   ei    = (const int*)  d_in[1];
    const float* W1    = (const float*)d_in[2];
    const float* atts1 = (const float*)d_in[3];
    const float* attd1 = (const float*)d_in[4];
    const float* b1    = (const float*)d_in[5];
    const float* W2    = (const float*)d_in[6];
    const float* atts2 = (const float*)d_in[7];
    const float* attd2 = (const float*)d_in[8];
    const float* b2    = (const float*)d_in[9];
    const float* bn_g  = (const float*)d_in[10];
    const float* bn_b  = (const float*)d_in[11];
    const float* bn_m  = (const float*)d_in[12];
    const float* bn_v  = (const float*)d_in[13];

    const int N = in_sizes[0] / 64;     // 100000
    const int E = in_sizes[1] / 2;      // 1600000
    const int T = E + N;
    const int NBK = (N + 255) >> BK_SHIFT;            // 256-node buckets
    const int NCH = (T + CHUNK - 1) / CHUNK;          // binning blocks
    const int NGB = (N + 7) / 8;                      // gemm blocks

    // workspace layout (manual alignment)
    char* p = (char*)d_ws;
    auto alloc = [&](size_t bytes, size_t align) -> void* {
        uintptr_t q = ((uintptr_t)p + align - 1) & ~(uintptr_t)(align - 1);
        p = (char*)(q + bytes);
        return (void*)q;
    };
    _Float16* h0      = (_Float16*)alloc((size_t)N * 128 * 2, 16);
    float* as1        = (float*)alloc((size_t)N * 4 * 4, 16);
    float* ad1        = (float*)alloc((size_t)N * 4 * 4, 16);
    float* h2         = (float*)alloc((size_t)N * 4, 16);
    float* pre0       = (float*)alloc(128 * 4, 16);
    float* pre1       = (float*)alloc(128 * 4, 16);
    int*   row_beg    = (int*)alloc((size_t)N * 4, 16);
    int*   row_end    = (int*)alloc((size_t)N * 4, 16);
    int*   bucket_cur = (int*)alloc((size_t)MAXBK * 4, 16);
    unsigned int* binned = (unsigned int*)alloc((size_t)NBK * CAP * 4, 16);
    int*   csr_src    = (int*)alloc((size_t)NBK * CAP * 4, 16);

    prep_kernel<<<1, 512, 0, stream>>>(b1, bn_g, bn_b, bn_m, bn_v,
                                       pre0, pre1, bucket_cur);

    bin_kernel<<<NCH, 256, 0, stream>>>(ei, E, N, NBK, bucket_cur, binned);

    csr_gemm_kernel<<<NBK + NGB, 256, 0, stream>>>(
        binned, bucket_cur, row_beg, row_end, csr_src, NBK,
        x, W1, atts1, attd1, h0, as1, ad1, N);

    gather1_kernel<<<(N + 3) / 4, 256, 0, stream>>>(
        row_beg, row_end, csr_src, (const half4*)h0, as1, ad1, pre0, pre1,
        W2, h2, N);

    gather2_kernel<<<(N + 15) / 16, 256, 0, stream>>>(
        row_beg, row_end, csr_src, h2, atts2, attd2, b2, (float*)d_out, N);
}

// Round 13
// 278.209 us; speedup vs baseline: 1.0293x; 1.0293x over previous
//
#include <hip/hip_runtime.h>
#include <cstdint>
#include <cstddef>

#define NEG_SLOPE 0.2f
#define BN_EPS 1e-5f
#define BK_SHIFT 8          // 256 nodes per bucket
#define MAXBK 512           // supports N <= 131072
#define CHUNK 4096          // edges per binning block (R11=8192 was the long pole)
#define CAP 8192            // slots per bucket (mean fill 4352, +58 sigma)

typedef _Float16 half4 __attribute__((ext_vector_type(4)));

// ---------------------------------------------------------------------------
// K0: fold b1 + BN(eval) into per-channel scale/shift, zero bucket cursors.
// ---------------------------------------------------------------------------
__global__ void prep_kernel(const float* __restrict__ b1,
                            const float* __restrict__ bn_gamma,
                            const float* __restrict__ bn_beta,
                            const float* __restrict__ bn_mean,
                            const float* __restrict__ bn_var,
                            float* __restrict__ pre0,
                            float* __restrict__ pre1,
                            int* __restrict__ bucket_cursor) {
    int t = threadIdx.x;            // 512 threads
    if (t < 128) {
        float sc = rsqrtf(bn_var[t] + BN_EPS) * bn_gamma[t];
        pre0[t] = sc;
        pre1[t] = (b1[t] - bn_mean[t]) * sc + bn_beta[t];
    }
    if (t < MAXBK) bucket_cursor[t] = 0;
}

// ---------------------------------------------------------------------------
// K1 (fused): blockIdx < NCH  -> binning pass; else gemm1.
// (R11-proven partition: gemm hides behind the bin tail; csr stays
// standalone. R12's bin/csr_gemm re-partition regressed — reverted.)
// bin: LDS histogram over 256-node buckets -> one reservation per
// (block,bucket) -> compact packed writes  word = (dst&255)<<24 | src.
// gemm: h0[N,128] = x@W1 (fp16 store), fused as1/ad1 epilogue.
// ---------------------------------------------------------------------------
__global__ void gemm_bin_kernel(// gemm args
                                const float* __restrict__ x,
                                const float* __restrict__ W1,
                                const float* __restrict__ att_s,
                                const float* __restrict__ att_d,
                                _Float16* __restrict__ h0,
                                float* __restrict__ as1,
                                float* __restrict__ ad1,
                                int N,
                                // bin args
                                const int* __restrict__ ei, int E, int NBK,
                                int* __restrict__ bucket_cursor,
                                unsigned int* __restrict__ binned,
                                int NCH) {
    __shared__ int cnt[MAXBK];
    __shared__ int gstart[MAXBK];
    __shared__ int cur[MAXBK];
    if (blockIdx.x < NCH) {
        int T = E + N;
        for (int b = threadIdx.x; b < NBK; b += 256) { cnt[b] = 0; cur[b] = 0; }
        __syncthreads();
        int base = blockIdx.x * CHUNK;
        for (int k = 0; k < CHUNK; k += 256) {
            int i = base + k + threadIdx.x;
            if (i < T) {
                int dst = (i < E) ? ei[E + i] : (i - E);
                atomicAdd(&cnt[dst >> BK_SHIFT], 1);
            }
        }
        __syncthreads();
        for (int b = threadIdx.x; b < NBK; b += 256) {
            int c = cnt[b];
            if (c) gstart[b] = atomicAdd(&bucket_cursor[b], c);
        }
        __syncthreads();
        for (int k = 0; k < CHUNK; k += 256) {
            int i = base + k + threadIdx.x;
            if (i < T) {
                int src, dst;
                if (i < E) { src = ei[i]; dst = ei[E + i]; }
                else       { src = i - E; dst = src; }
                int b = dst >> BK_SHIFT;
                int lp = gstart[b] + atomicAdd(&cur[b], 1);
                if (lp < CAP)   // overflow guard (statistically impossible)
                    binned[(size_t)b * CAP + lp] =
                        (unsigned int)src | ((unsigned int)(dst & 255) << 24);
            }
        }
        return;
    }
    // ----- gemm path: 4 nodes per thread (W1 reuse x4), fp16 h0 store
    int bid = blockIdx.x - NCH;
    int c = threadIdx.x & 127;
    int pair = __builtin_amdgcn_readfirstlane(threadIdx.x >> 7);
    int n0 = (bid * 2 + pair) * 4;
    if (n0 >= N) return;
    float acc[4] = {0.f, 0.f, 0.f, 0.f};
    const float* __restrict__ xr = x + (size_t)n0 * 64;
    int nn = N - n0; if (nn > 4) nn = 4;
    if (nn == 4) {
#pragma unroll
        for (int k = 0; k < 64; ++k) {
            float w = W1[k * 128 + c];
            acc[0] = fmaf(xr[k],       w, acc[0]);
            acc[1] = fmaf(xr[64 + k],  w, acc[1]);
            acc[2] = fmaf(xr[128 + k], w, acc[2]);
            acc[3] = fmaf(xr[192 + k], w, acc[3]);
        }
    } else {
        for (int i = 0; i < nn; ++i)
            for (int k = 0; k < 64; ++k)
                acc[i] = fmaf(xr[i * 64 + k], W1[k * 128 + c], acc[i]);
    }
    float asc = att_s[c], adc = att_d[c];
    int head = c >> 5;
#pragma unroll
    for (int i = 0; i < 4; ++i) {
        if (i >= nn) break;
        int n = n0 + i;
        h0[(size_t)n * 128 + c] = (_Float16)acc[i];
        float s = acc[i] * asc;
        float d = acc[i] * adc;
#pragma unroll
        for (int off = 16; off >= 1; off >>= 1) {
            s += __shfl_xor(s, off);
            d += __shfl_xor(d, off);
        }
        if ((threadIdx.x & 31) == 0) {
            as1[(size_t)n * 4 + head] = s;
            ad1[(size_t)n * 4 + head] = d;
        }
    }
}

// ---------------------------------------------------------------------------
// K2: per-bucket finalize (R8-proven). One block per bucket: LDS per-node
// count -> scan -> row_beg/row_end, then scatter src into the bucket's
// contiguous region of csr_src.
// ---------------------------------------------------------------------------
__global__ void csr_kernel(const unsigned int* __restrict__ binned,
                           const int* __restrict__ bucket_cursor,
                           int N,
                           int* __restrict__ row_beg,
                           int* __restrict__ row_end,
                           int* __restrict__ csr_src) {
    __shared__ int cnt[256];
    __shared__ int loc[256];
    __shared__ int cur[256];
    int b = blockIdx.x;
    int tid = threadIdx.x;          // 256 threads
    int n0 = b << BK_SHIFT;
    int nr = N - n0; if (nr > 256) nr = 256;
    int tot = bucket_cursor[b];
    if (tot > CAP) tot = CAP;
    size_t base = (size_t)b * CAP;
    cnt[tid] = 0;
    __syncthreads();
    for (int j = tid; j < tot; j += 256) {
        atomicAdd(&cnt[binned[base + j] >> 24], 1);
    }
    __syncthreads();
    int v = cnt[tid];
    loc[tid] = v;
    __syncthreads();
    for (int off = 1; off < 256; off <<= 1) {
        int t = (tid >= off) ? loc[tid - off] : 0;
        __syncthreads();
        loc[tid] += t;
        __syncthreads();
    }
    int excl = loc[tid] - v;
    cur[tid] = excl;
    if (tid < nr) {
        row_beg[n0 + tid] = (int)base + excl;
        row_end[n0 + tid] = (int)base + excl + v;
    }
    __syncthreads();
    for (int j = tid; j < tot; j += 256) {
        unsigned int w = binned[base + j];
        int pos = atomicAdd(&cur[w >> 24], 1);
        csr_src[base + pos] = (int)(w & 0xFFFFFFu);
    }
}

// ---------------------------------------------------------------------------
// K3: layer-1 gather + finalize — the R5/R7-PROVEN body, unchanged.
// ONE WAVE per dst node (block 256 = 4 nodes); 2x32-lane edge-groups;
// half4 (8B dwordx2) h0 loads; redundant-but-overlappable exp per 8-lane
// head group; register accumulators; shfl combine; prefolded pre0/pre1.
// (R6 half8/16-lane, R9 two-phase LDS, R10 LDS-atomic variants all
// regressed — do not restructure this loop.)
// ---------------------------------------------------------------------------
__global__ void gather1_kernel(const int* __restrict__ row_beg,
                               const int* __restrict__ row_end,
                               const int* __restrict__ csr_src,
                               const half4* __restrict__ h0,
                               const float* __restrict__ as1,
                               const float* __restrict__ ad1,
                               const float* __restrict__ pre0,
                               const float* __restrict__ pre1,
                               const float* __restrict__ W2,
                               float* __restrict__ h2, int N) {
    int n = blockIdx.x * 4 + (threadIdx.x >> 6);
    if (n >= N) return;
    int lane = threadIdx.x & 63;
    int sub  = lane & 31;           // half4 index within the 128-ch row
    int grp  = lane >> 5;           // which edge of the pair
    int head = sub >> 3;            // channels 4*sub..4*sub+3 are in this head
    float ad = ad1[(size_t)n * 4 + head];
    int beg = row_beg[n];
    int end = row_end[n];
    float4 acc = make_float4(0.f, 0.f, 0.f, 0.f);
    float den = 0.f;
#pragma unroll 2
    for (int j = beg + grp; j < end; j += 2) {
        int src = csr_src[j];
        float as = as1[(size_t)src * 4 + head];
        float lg = as + ad;
        float l = fmaf(NEG_SLOPE, fminf(lg, 0.f), fmaxf(lg, 0.f));
        float w = __expf(l);
        half4 hv = h0[(size_t)src * 32 + sub];
        acc.x = fmaf(w, (float)hv.x, acc.x);
        acc.y = fmaf(w, (float)hv.y, acc.y);
        acc.z = fmaf(w, (float)hv.z, acc.z);
        acc.w = fmaf(w, (float)hv.w, acc.w);
        den += w;
    }
    acc.x += __shfl_xor(acc.x, 32);
    acc.y += __shfl_xor(acc.y, 32);
    acc.z += __shfl_xor(acc.z, 32);
    acc.w += __shfl_xor(acc.w, 32);
    den   += __shfl_xor(den, 32);
    float inv = 1.f / (den + 1e-16f);
    int c = sub * 4;
    float v0 = fmaf(acc.x * inv, pre0[c],     pre1[c]);
    float v1 = fmaf(acc.y * inv, pre0[c + 1], pre1[c + 1]);
    float v2 = fmaf(acc.z * inv, pre0[c + 2], pre1[c + 2]);
    float v3 = fmaf(acc.w * inv, pre0[c + 3], pre1[c + 3]);
    v0 = v0 > 0.f ? v0 : expm1f(v0);
    v1 = v1 > 0.f ? v1 : expm1f(v1);
    v2 = v2 > 0.f ? v2 : expm1f(v2);
    v3 = v3 > 0.f ? v3 : expm1f(v3);
    float t = v0 * W2[c] + v1 * W2[c + 1] + v2 * W2[c + 2] + v3 * W2[c + 3];
#pragma unroll
    for (int off = 16; off >= 1; off >>= 1) t += __shfl_xor(t, off);
    if (lane == 0) h2[n] = t;
}

// ---------------------------------------------------------------------------
// K4: layer-2 gather (R7-proven). 16-lane group per dst node
// (block 256 = 16 nodes); mean degree ~17 -> lanes ~fully utilized.
// ---------------------------------------------------------------------------
__global__ void gather2_kernel(const int* __restrict__ row_beg,
                               const int* __restrict__ row_end,
                               const int* __restrict__ csr_src,
                               const float* __restrict__ h2,
                               const float* __restrict__ att_s2,
                               const float* __restrict__ att_d2,
                               const float* __restrict__ b2,
                               float* __restrict__ out, int N) {
    int n = blockIdx.x * 16 + (threadIdx.x >> 4);
    if (n >= N) return;
    int lane = threadIdx.x & 15;
    int beg = row_beg[n];
    int end = row_end[n];
    float a_s = att_s2[0];
    float a_d = att_d2[0];
    float hd = h2[n];
    float num = 0.f, den = 0.f;
    for (int j = beg + lane; j < end; j += 16) {
        int src = csr_src[j];
        float hs = h2[src];
        float lg = hs * a_s + hd * a_d;
        float l = fmaf(NEG_SLOPE, fminf(lg, 0.f), fmaxf(lg, 0.f));
        float w = __expf(l);
        num += w * hs;
        den += w;
    }
#pragma unroll
    for (int off = 8; off >= 1; off >>= 1) {
        num += __shfl_xor(num, off);
        den += __shfl_xor(den, off);
    }
    if (lane == 0) out[n] = num / (den + 1e-16f) + b2[0];
}

extern "C" void kernel_launch(void* const* d_in, const int* in_sizes, int n_in,
                              void* d_out, int out_size, void* d_ws, size_t ws_size,
                              hipStream_t stream) {
    const float* x     = (const float*)d_in[0];
    const int*   ei    = (const int*)  d_in[1];
    const float* W1    = (const float*)d_in[2];
    const float* atts1 = (const float*)d_in[3];
    const float* attd1 = (const float*)d_in[4];
    const float* b1    = (const float*)d_in[5];
    const float* W2    = (const float*)d_in[6];
    const float* atts2 = (const float*)d_in[7];
    const float* attd2 = (const float*)d_in[8];
    const float* b2    = (const float*)d_in[9];
    const float* bn_g  = (const float*)d_in[10];
    const float* bn_b  = (const float*)d_in[11];
    const float* bn_m  = (const float*)d_in[12];
    const float* bn_v  = (const float*)d_in[13];

    const int N = in_sizes[0] / 64;     // 100000
    const int E = in_sizes[1] / 2;      // 1600000
    const int T = E + N;
    const int NBK = (N + 255) >> BK_SHIFT;            // 256-node buckets
    const int NCH = (T + CHUNK - 1) / CHUNK;          // binning blocks
    const int NGB = (N + 7) / 8;                      // gemm blocks

    // workspace layout (manual alignment)
    char* p = (char*)d_ws;
    auto alloc = [&](size_t bytes, size_t align) -> void* {
        uintptr_t q = ((uintptr_t)p + align - 1) & ~(uintptr_t)(align - 1);
        p = (char*)(q + bytes);
        return (void*)q;
    };
    _Float16* h0      = (_Float16*)alloc((size_t)N * 128 * 2, 16);
    float* as1        = (float*)alloc((size_t)N * 4 * 4, 16);
    float* ad1        = (float*)alloc((size_t)N * 4 * 4, 16);
    float* h2         = (float*)alloc((size_t)N * 4, 16);
    float* pre0       = (float*)alloc(128 * 4, 16);
    float* pre1       = (float*)alloc(128 * 4, 16);
    int*   row_beg    = (int*)alloc((size_t)N * 4, 16);
    int*   row_end    = (int*)alloc((size_t)N * 4, 16);
    int*   bucket_cur = (int*)alloc((size_t)MAXBK * 4, 16);
    unsigned int* binned = (unsigned int*)alloc((size_t)NBK * CAP * 4, 16);
    int*   csr_src    = (int*)alloc((size_t)NBK * CAP * 4, 16);

    prep_kernel<<<1, 512, 0, stream>>>(b1, bn_g, bn_b, bn_m, bn_v,
                                       pre0, pre1, bucket_cur);

    gemm_bin_kernel<<<NCH + NGB, 256, 0, stream>>>(
        x, W1, atts1, attd1, h0, as1, ad1, N,
        ei, E, NBK, bucket_cur, binned, NCH);

    csr_kernel<<<NBK, 256, 0, stream>>>(binned, bucket_cur, N,
                                        row_beg, row_end, csr_src);

    gather1_kernel<<<(N + 3) / 4, 256, 0, stream>>>(
        row_beg, row_end, csr_src, (const half4*)h0, as1, ad1, pre0, pre1,
        W2, h2, N);

    gather2_kernel<<<(N + 15) / 16, 256, 0, stream>>>(
        row_beg, row_end, csr_src, h2, atts2, attd2, b2, (float*)d_out, N);
}

// Round 14
// 273.928 us; speedup vs baseline: 1.0454x; 1.0156x over previous
//
#include <hip/hip_runtime.h>
#include <cstdint>
#include <cstddef>

#define NEG_SLOPE 0.2f
#define BN_EPS 1e-5f
#define BK_SHIFT 6          // 64 nodes per bucket (csr parallelism: 1563 blocks)
#define MAXBK 2048          // supports N <= 131072
#define CHUNK 8192          // edges per binning block (R11-proven)
#define CAP 2048            // slots per bucket (mean fill ~1088, +29 sigma)

typedef _Float16 half4 __attribute__((ext_vector_type(4)));

// ---------------------------------------------------------------------------
// K0: fold b1 + BN(eval) into per-channel scale/shift, zero bucket cursors.
// ---------------------------------------------------------------------------
__global__ void prep_kernel(const float* __restrict__ b1,
                            const float* __restrict__ bn_gamma,
                            const float* __restrict__ bn_beta,
                            const float* __restrict__ bn_mean,
                            const float* __restrict__ bn_var,
                            float* __restrict__ pre0,
                            float* __restrict__ pre1,
                            int* __restrict__ bucket_cursor) {
    int t = threadIdx.x;            // 512 threads
    if (t < 128) {
        float sc = rsqrtf(bn_var[t] + BN_EPS) * bn_gamma[t];
        pre0[t] = sc;
        pre1[t] = (b1[t] - bn_mean[t]) * sc + bn_beta[t];
    }
    for (int i = t; i < MAXBK; i += 512) bucket_cursor[i] = 0;
}

// ---------------------------------------------------------------------------
// K1 (fused): blockIdx < NCH  -> binning pass; else gemm1.
// (R11-proven partition: gemm hides behind the bin tail; csr standalone.)
// bin: LDS histogram over 64-node buckets -> one reservation per
// (block,bucket) -> compact packed writes  word = (dst&63)<<24 | src.
// gemm: h0[N,128] = x@W1 (fp16 store), fused as1/ad1 epilogue.
// ---------------------------------------------------------------------------
__global__ void gemm_bin_kernel(// gemm args
                                const float* __restrict__ x,
                                const float* __restrict__ W1,
                                const float* __restrict__ att_s,
                                const float* __restrict__ att_d,
                                _Float16* __restrict__ h0,
                                float* __restrict__ as1,
                                float* __restrict__ ad1,
                                int N,
                                // bin args
                                const int* __restrict__ ei, int E, int NBK,
                                int* __restrict__ bucket_cursor,
                                unsigned int* __restrict__ binned,
                                int NCH) {
    __shared__ int cnt[MAXBK];
    __shared__ int gstart[MAXBK];
    __shared__ int cur[MAXBK];
    if (blockIdx.x < NCH) {
        int T = E + N;
        for (int b = threadIdx.x; b < NBK; b += 256) { cnt[b] = 0; cur[b] = 0; }
        __syncthreads();
        int base = blockIdx.x * CHUNK;
        for (int k = 0; k < CHUNK; k += 256) {
            int i = base + k + threadIdx.x;
            if (i < T) {
                int dst = (i < E) ? ei[E + i] : (i - E);
                atomicAdd(&cnt[dst >> BK_SHIFT], 1);
            }
        }
        __syncthreads();
        for (int b = threadIdx.x; b < NBK; b += 256) {
            int c = cnt[b];
            if (c) gstart[b] = atomicAdd(&bucket_cursor[b], c);
        }
        __syncthreads();
        for (int k = 0; k < CHUNK; k += 256) {
            int i = base + k + threadIdx.x;
            if (i < T) {
                int src, dst;
                if (i < E) { src = ei[i]; dst = ei[E + i]; }
                else       { src = i - E; dst = src; }
                int b = dst >> BK_SHIFT;
                int lp = gstart[b] + atomicAdd(&cur[b], 1);
                if (lp < CAP)   // overflow guard (statistically impossible)
                    binned[(size_t)b * CAP + lp] =
                        (unsigned int)src | ((unsigned int)(dst & 63) << 24);
            }
        }
        return;
    }
    // ----- gemm path: 4 nodes per thread (W1 reuse x4), fp16 h0 store
    int bid = blockIdx.x - NCH;
    int c = threadIdx.x & 127;
    int pair = __builtin_amdgcn_readfirstlane(threadIdx.x >> 7);
    int n0 = (bid * 2 + pair) * 4;
    if (n0 >= N) return;
    float acc[4] = {0.f, 0.f, 0.f, 0.f};
    const float* __restrict__ xr = x + (size_t)n0 * 64;
    int nn = N - n0; if (nn > 4) nn = 4;
    if (nn == 4) {
#pragma unroll
        for (int k = 0; k < 64; ++k) {
            float w = W1[k * 128 + c];
            acc[0] = fmaf(xr[k],       w, acc[0]);
            acc[1] = fmaf(xr[64 + k],  w, acc[1]);
            acc[2] = fmaf(xr[128 + k], w, acc[2]);
            acc[3] = fmaf(xr[192 + k], w, acc[3]);
        }
    } else {
        for (int i = 0; i < nn; ++i)
            for (int k = 0; k < 64; ++k)
                acc[i] = fmaf(xr[i * 64 + k], W1[k * 128 + c], acc[i]);
    }
    float asc = att_s[c], adc = att_d[c];
    int head = c >> 5;
#pragma unroll
    for (int i = 0; i < 4; ++i) {
        if (i >= nn) break;
        int n = n0 + i;
        h0[(size_t)n * 128 + c] = (_Float16)acc[i];
        float s = acc[i] * asc;
        float d = acc[i] * adc;
#pragma unroll
        for (int off = 16; off >= 1; off >>= 1) {
            s += __shfl_xor(s, off);
            d += __shfl_xor(d, off);
        }
        if ((threadIdx.x & 31) == 0) {
            as1[(size_t)n * 4 + head] = s;
            ad1[(size_t)n * 4 + head] = d;
        }
    }
}

// ---------------------------------------------------------------------------
// K2: per-bucket finalize. One block per 64-node bucket (1563 blocks -> 6/CU
// vs R11's 391 -> 1.5/CU, which made this a hidden ~55-65us serial hog).
// LDS per-node count -> scan -> row_beg/row_end -> in-bucket scatter.
// ---------------------------------------------------------------------------
__global__ void csr_kernel(const unsigned int* __restrict__ binned,
                           const int* __restrict__ bucket_cursor,
                           int N,
                           int* __restrict__ row_beg,
                           int* __restrict__ row_end,
                           int* __restrict__ csr_src) {
    __shared__ int cnt[64];
    __shared__ int loc[64];
    __shared__ int cur[64];
    int b = blockIdx.x;
    int tid = threadIdx.x;          // 256 threads
    int n0 = b << BK_SHIFT;
    int nr = N - n0; if (nr > 64) nr = 64;
    int tot = bucket_cursor[b];
    if (tot > CAP) tot = CAP;
    size_t base = (size_t)b * CAP;
    if (tid < 64) cnt[tid] = 0;
    __syncthreads();
    for (int j = tid; j < tot; j += 256) {
        atomicAdd(&cnt[binned[base + j] >> 24], 1);
    }
    __syncthreads();
    if (tid < 64) loc[tid] = cnt[tid];
    __syncthreads();
    for (int off = 1; off < 64; off <<= 1) {
        int t = 0;
        if (tid < 64 && tid >= off) t = loc[tid - off];
        __syncthreads();
        if (tid < 64) loc[tid] += t;
        __syncthreads();
    }
    if (tid < 64) {
        int v = cnt[tid];
        int excl = loc[tid] - v;
        cur[tid] = excl;
        if (tid < nr) {
            row_beg[n0 + tid] = (int)base + excl;
            row_end[n0 + tid] = (int)base + excl + v;
        }
    }
    __syncthreads();
    for (int j = tid; j < tot; j += 256) {
        unsigned int w = binned[base + j];
        int pos = atomicAdd(&cur[w >> 24], 1);
        csr_src[base + pos] = (int)(w & 0xFFFFFFu);
    }
}

// ---------------------------------------------------------------------------
// K3: layer-1 gather + finalize — the R5/R7-PROVEN body, unchanged.
// ONE WAVE per dst node (block 256 = 4 nodes); 2x32-lane edge-groups;
// half4 (8B dwordx2) h0 loads; redundant-but-overlappable exp per 8-lane
// head group; register accumulators; shfl combine; prefolded pre0/pre1.
// (R6 half8/16-lane, R9 two-phase LDS, R10 LDS-atomic variants all
// regressed — do not restructure this loop.)
// ---------------------------------------------------------------------------
__global__ void gather1_kernel(const int* __restrict__ row_beg,
                               const int* __restrict__ row_end,
                               const int* __restrict__ csr_src,
                               const half4* __restrict__ h0,
                               const float* __restrict__ as1,
                               const float* __restrict__ ad1,
                               const float* __restrict__ pre0,
                               const float* __restrict__ pre1,
                               const float* __restrict__ W2,
                               float* __restrict__ h2, int N) {
    int n = blockIdx.x * 4 + (threadIdx.x >> 6);
    if (n >= N) return;
    int lane = threadIdx.x & 63;
    int sub  = lane & 31;           // half4 index within the 128-ch row
    int grp  = lane >> 5;           // which edge of the pair
    int head = sub >> 3;            // channels 4*sub..4*sub+3 are in this head
    float ad = ad1[(size_t)n * 4 + head];
    int beg = row_beg[n];
    int end = row_end[n];
    float4 acc = make_float4(0.f, 0.f, 0.f, 0.f);
    float den = 0.f;
#pragma unroll 2
    for (int j = beg + grp; j < end; j += 2) {
        int src = csr_src[j];
        float as = as1[(size_t)src * 4 + head];
        float lg = as + ad;
        float l = fmaf(NEG_SLOPE, fminf(lg, 0.f), fmaxf(lg, 0.f));
        float w = __expf(l);
        half4 hv = h0[(size_t)src * 32 + sub];
        acc.x = fmaf(w, (float)hv.x, acc.x);
        acc.y = fmaf(w, (float)hv.y, acc.y);
        acc.z = fmaf(w, (float)hv.z, acc.z);
        acc.w = fmaf(w, (float)hv.w, acc.w);
        den += w;
    }
    acc.x += __shfl_xor(acc.x, 32);
    acc.y += __shfl_xor(acc.y, 32);
    acc.z += __shfl_xor(acc.z, 32);
    acc.w += __shfl_xor(acc.w, 32);
    den   += __shfl_xor(den, 32);
    float inv = 1.f / (den + 1e-16f);
    int c = sub * 4;
    float v0 = fmaf(acc.x * inv, pre0[c],     pre1[c]);
    float v1 = fmaf(acc.y * inv, pre0[c + 1], pre1[c + 1]);
    float v2 = fmaf(acc.z * inv, pre0[c + 2], pre1[c + 2]);
    float v3 = fmaf(acc.w * inv, pre0[c + 3], pre1[c + 3]);
    v0 = v0 > 0.f ? v0 : expm1f(v0);
    v1 = v1 > 0.f ? v1 : expm1f(v1);
    v2 = v2 > 0.f ? v2 : expm1f(v2);
    v3 = v3 > 0.f ? v3 : expm1f(v3);
    float t = v0 * W2[c] + v1 * W2[c + 1] + v2 * W2[c + 2] + v3 * W2[c + 3];
#pragma unroll
    for (int off = 16; off >= 1; off >>= 1) t += __shfl_xor(t, off);
    if (lane == 0) h2[n] = t;
}

// ---------------------------------------------------------------------------
// K4: layer-2 gather (R7-proven). 16-lane group per dst node
// (block 256 = 16 nodes); mean degree ~17 -> lanes ~fully utilized.
// ---------------------------------------------------------------------------
__global__ void gather2_kernel(const int* __restrict__ row_beg,
                               const int* __restrict__ row_end,
                               const int* __restrict__ csr_src,
                               const float* __restrict__ h2,
                               const float* __restrict__ att_s2,
                               const float* __restrict__ att_d2,
                               const float* __restrict__ b2,
                               float* __restrict__ out, int N) {
    int n = blockIdx.x * 16 + (threadIdx.x >> 4);
    if (n >= N) return;
    int lane = threadIdx.x & 15;
    int beg = row_beg[n];
    int end = row_end[n];
    float a_s = att_s2[0];
    float a_d = att_d2[0];
    float hd = h2[n];
    float num = 0.f, den = 0.f;
    for (int j = beg + lane; j < end; j += 16) {
        int src = csr_src[j];
        float hs = h2[src];
        float lg = hs * a_s + hd * a_d;
        float l = fmaf(NEG_SLOPE, fminf(lg, 0.f), fmaxf(lg, 0.f));
        float w = __expf(l);
        num += w * hs;
        den += w;
    }
#pragma unroll
    for (int off = 8; off >= 1; off >>= 1) {
        num += __shfl_xor(num, off);
        den += __shfl_xor(den, off);
    }
    if (lane == 0) out[n] = num / (den + 1e-16f) + b2[0];
}

extern "C" void kernel_launch(void* const* d_in, const int* in_sizes, int n_in,
                              void* d_out, int out_size, void* d_ws, size_t ws_size,
                              hipStream_t stream) {
    const float* x     = (const float*)d_in[0];
    const int*   ei    = (const int*)  d_in[1];
    const float* W1    = (const float*)d_in[2];
    const float* atts1 = (const float*)d_in[3];
    const float* attd1 = (const float*)d_in[4];
    const float* b1    = (const float*)d_in[5];
    const float* W2    = (const float*)d_in[6];
    const float* atts2 = (const float*)d_in[7];
    const float* attd2 = (const float*)d_in[8];
    const float* b2    = (const float*)d_in[9];
    const float* bn_g  = (const float*)d_in[10];
    const float* bn_b  = (const float*)d_in[11];
    const float* bn_m  = (const float*)d_in[12];
    const float* bn_v  = (const float*)d_in[13];

    const int N = in_sizes[0] / 64;     // 100000
    const int E = in_sizes[1] / 2;      // 1600000
    const int T = E + N;
    const int NBK = (N + 63) >> BK_SHIFT;             // 64-node buckets
    const int NCH = (T + CHUNK - 1) / CHUNK;          // binning blocks
    const int NGB = (N + 7) / 8;                      // gemm blocks

    // workspace layout (manual alignment)
    char* p = (char*)d_ws;
    auto alloc = [&](size_t bytes, size_t align) -> void* {
        uintptr_t q = ((uintptr_t)p + align - 1) & ~(uintptr_t)(align - 1);
        p = (char*)(q + bytes);
        return (void*)q;
    };
    _Float16* h0      = (_Float16*)alloc((size_t)N * 128 * 2, 16);
    float* as1        = (float*)alloc((size_t)N * 4 * 4, 16);
    float* ad1        = (float*)alloc((size_t)N * 4 * 4, 16);
    float* h2         = (float*)alloc((size_t)N * 4, 16);
    float* pre0       = (float*)alloc(128 * 4, 16);
    float* pre1       = (float*)alloc(128 * 4, 16);
    int*   row_beg    = (int*)alloc((size_t)N * 4, 16);
    int*   row_end    = (int*)alloc((size_t)N * 4, 16);
    int*   bucket_cur = (int*)alloc((size_t)MAXBK * 4, 16);
    unsigned int* binned = (unsigned int*)alloc((size_t)NBK * CAP * 4, 16);
    int*   csr_src    = (int*)alloc((size_t)NBK * CAP * 4, 16);

    prep_kernel<<<1, 512, 0, stream>>>(b1, bn_g, bn_b, bn_m, bn_v,
                                       pre0, pre1, bucket_cur);

    gemm_bin_kernel<<<NCH + NGB, 256, 0, stream>>>(
        x, W1, atts1, attd1, h0, as1, ad1, N,
        ei, E, NBK, bucket_cur, binned, NCH);

    csr_kernel<<<NBK, 256, 0, stream>>>(binned, bucket_cur, N,
                                        row_beg, row_end, csr_src);

    gather1_kernel<<<(N + 3) / 4, 256, 0, stream>>>(
        row_beg, row_end, csr_src, (const half4*)h0, as1, ad1, pre0, pre1,
        W2, h2, N);

    gather2_kernel<<<(N + 15) / 16, 256, 0, stream>>>(
        row_beg, row_end, csr_src, h2, atts2, attd2, b2, (float*)d_out, N);
}

// Round 15
// 266.825 us; speedup vs baseline: 1.0733x; 1.0266x over previous
//
#include <hip/hip_runtime.h>
#include <cstdint>
#include <cstddef>

#define NEG_SLOPE 0.2f
#define BN_EPS 1e-5f
#define BK_SHIFT 8          // 256 nodes per bucket (bin-optimal; R14's 64 hurt bin)
#define MAXBK 512           // supports N <= 131072
#define CHUNK 8192          // edges per binning block (CHUNK sweep was flat)
#define CAP 8192            // slots per bucket (mean fill 4352, +58 sigma)

typedef _Float16 half4 __attribute__((ext_vector_type(4)));

// ---------------------------------------------------------------------------
// K0: fold b1 + BN(eval) into per-channel scale/shift, zero bucket cursors.
// ---------------------------------------------------------------------------
__global__ void prep_kernel(const float* __restrict__ b1,
                            const float* __restrict__ bn_gamma,
                            const float* __restrict__ bn_beta,
                            const float* __restrict__ bn_mean,
                            const float* __restrict__ bn_var,
                            float* __restrict__ pre0,
                            float* __restrict__ pre1,
                            int* __restrict__ bucket_cursor) {
    int t = threadIdx.x;            // 512 threads
    if (t < 128) {
        float sc = rsqrtf(bn_var[t] + BN_EPS) * bn_gamma[t];
        pre0[t] = sc;
        pre1[t] = (b1[t] - bn_mean[t]) * sc + bn_beta[t];
    }
    if (t < MAXBK) bucket_cursor[t] = 0;
}

// ---------------------------------------------------------------------------
// K1 (fused): blockIdx < NCH  -> binning pass; else gemm1.
// bin: LDS histogram over 256-node buckets -> one reservation per
// (block,bucket) -> compact packed writes  word = (dst&255)<<24 | src.
// NEW: guard-free unroll-x4 fast path for chunks fully below E — batches 4
// independent ei loads before the LDS atomics (bin blocks are latency-bound
// on the load->atomic chain: VALU 28%, CHUNK sweep flat).
// gemm: h0[N,128] = x@W1 (fp16 store), fused as1/ad1 epilogue.
// ---------------------------------------------------------------------------
__global__ void gemm_bin_kernel(// gemm args
                                const float* __restrict__ x,
                                const float* __restrict__ W1,
                                const float* __restrict__ att_s,
                                const float* __restrict__ att_d,
                                _Float16* __restrict__ h0,
                                float* __restrict__ as1,
                                float* __restrict__ ad1,
                                int N,
                                // bin args
                                const int* __restrict__ ei, int E, int NBK,
                                int* __restrict__ bucket_cursor,
                                unsigned int* __restrict__ binned,
                                int NCH) {
    __shared__ int cnt[MAXBK];
    __shared__ int gstart[MAXBK];
    __shared__ int cur[MAXBK];
    if (blockIdx.x < NCH) {
        int T = E + N;
        int tid = threadIdx.x;
        for (int b = tid; b < NBK; b += 256) { cnt[b] = 0; cur[b] = 0; }
        __syncthreads();
        int base = blockIdx.x * CHUNK;
        bool fast = (base + CHUNK <= E);    // whole chunk is real edges
        if (fast) {
            // ---- count pass, 4 loads in flight per iteration
            for (int k = 0; k < CHUNK; k += 1024) {
                int i0 = base + k + tid;
                int d0 = ei[E + i0];
                int d1 = ei[E + i0 + 256];
                int d2 = ei[E + i0 + 512];
                int d3 = ei[E + i0 + 768];
                atomicAdd(&cnt[d0 >> BK_SHIFT], 1);
                atomicAdd(&cnt[d1 >> BK_SHIFT], 1);
                atomicAdd(&cnt[d2 >> BK_SHIFT], 1);
                atomicAdd(&cnt[d3 >> BK_SHIFT], 1);
            }
        } else {
            for (int k = 0; k < CHUNK; k += 256) {
                int i = base + k + tid;
                if (i < T) {
                    int dst = (i < E) ? ei[E + i] : (i - E);
                    atomicAdd(&cnt[dst >> BK_SHIFT], 1);
                }
            }
        }
        __syncthreads();
        for (int b = tid; b < NBK; b += 256) {
            int c = cnt[b];
            if (c) gstart[b] = atomicAdd(&bucket_cursor[b], c);
        }
        __syncthreads();
        if (fast) {
            // ---- scatter pass, 8 loads in flight per iteration
            for (int k = 0; k < CHUNK; k += 1024) {
                int i0 = base + k + tid;
                int s0 = ei[i0];
                int s1 = ei[i0 + 256];
                int s2 = ei[i0 + 512];
                int s3 = ei[i0 + 768];
                int d0 = ei[E + i0];
                int d1 = ei[E + i0 + 256];
                int d2 = ei[E + i0 + 512];
                int d3 = ei[E + i0 + 768];
                int b0 = d0 >> BK_SHIFT, b1 = d1 >> BK_SHIFT;
                int b2 = d2 >> BK_SHIFT, b3 = d3 >> BK_SHIFT;
                int p0 = gstart[b0] + atomicAdd(&cur[b0], 1);
                int p1 = gstart[b1] + atomicAdd(&cur[b1], 1);
                int p2 = gstart[b2] + atomicAdd(&cur[b2], 1);
                int p3 = gstart[b3] + atomicAdd(&cur[b3], 1);
                if (p0 < CAP) binned[(size_t)b0 * CAP + p0] =
                    (unsigned int)s0 | ((unsigned int)(d0 & 255) << 24);
                if (p1 < CAP) binned[(size_t)b1 * CAP + p1] =
                    (unsigned int)s1 | ((unsigned int)(d1 & 255) << 24);
                if (p2 < CAP) binned[(size_t)b2 * CAP + p2] =
                    (unsigned int)s2 | ((unsigned int)(d2 & 255) << 24);
                if (p3 < CAP) binned[(size_t)b3 * CAP + p3] =
                    (unsigned int)s3 | ((unsigned int)(d3 & 255) << 24);
            }
        } else {
            for (int k = 0; k < CHUNK; k += 256) {
                int i = base + k + tid;
                if (i < T) {
                    int src, dst;
                    if (i < E) { src = ei[i]; dst = ei[E + i]; }
                    else       { src = i - E; dst = src; }
                    int b = dst >> BK_SHIFT;
                    int lp = gstart[b] + atomicAdd(&cur[b], 1);
                    if (lp < CAP)
                        binned[(size_t)b * CAP + lp] =
                            (unsigned int)src | ((unsigned int)(dst & 255) << 24);
                }
            }
        }
        return;
    }
    // ----- gemm path: 4 nodes per thread (W1 reuse x4), fp16 h0 store
    int bid = blockIdx.x - NCH;
    int c = threadIdx.x & 127;
    int pair = __builtin_amdgcn_readfirstlane(threadIdx.x >> 7);
    int n0 = (bid * 2 + pair) * 4;
    if (n0 >= N) return;
    float acc[4] = {0.f, 0.f, 0.f, 0.f};
    const float* __restrict__ xr = x + (size_t)n0 * 64;
    int nn = N - n0; if (nn > 4) nn = 4;
    if (nn == 4) {
#pragma unroll
        for (int k = 0; k < 64; ++k) {
            float w = W1[k * 128 + c];
            acc[0] = fmaf(xr[k],       w, acc[0]);
            acc[1] = fmaf(xr[64 + k],  w, acc[1]);
            acc[2] = fmaf(xr[128 + k], w, acc[2]);
            acc[3] = fmaf(xr[192 + k], w, acc[3]);
        }
    } else {
        for (int i = 0; i < nn; ++i)
            for (int k = 0; k < 64; ++k)
                acc[i] = fmaf(xr[i * 64 + k], W1[k * 128 + c], acc[i]);
    }
    float asc = att_s[c], adc = att_d[c];
    int head = c >> 5;
#pragma unroll
    for (int i = 0; i < 4; ++i) {
        if (i >= nn) break;
        int n = n0 + i;
        h0[(size_t)n * 128 + c] = (_Float16)acc[i];
        float s = acc[i] * asc;
        float d = acc[i] * adc;
#pragma unroll
        for (int off = 16; off >= 1; off >>= 1) {
            s += __shfl_xor(s, off);
            d += __shfl_xor(d, off);
        }
        if ((threadIdx.x & 31) == 0) {
            as1[(size_t)n * 4 + head] = s;
            ad1[(size_t)n * 4 + head] = d;
        }
    }
}

// ---------------------------------------------------------------------------
// K2: per-bucket finalize. 1024 threads/block (vs 256): serial passes drop
// 34 -> ~9 iterations per block — the R14 csr-parallelism win without
// shrinking bin's buckets. One block per 256-node bucket.
// ---------------------------------------------------------------------------
__global__ void csr_kernel(const unsigned int* __restrict__ binned,
                           const int* __restrict__ bucket_cursor,
                           int N,
                           int* __restrict__ row_beg,
                           int* __restrict__ row_end,
                           int* __restrict__ csr_src) {
    __shared__ int cnt[256];
    __shared__ int loc[256];
    __shared__ int cur[256];
    int b = blockIdx.x;
    int tid = threadIdx.x;          // 1024 threads
    int n0 = b << BK_SHIFT;
    int nr = N - n0; if (nr > 256) nr = 256;
    int tot = bucket_cursor[b];
    if (tot > CAP) tot = CAP;
    size_t base = (size_t)b * CAP;
    if (tid < 256) cnt[tid] = 0;
    __syncthreads();
    for (int j = tid; j < tot; j += 1024) {
        atomicAdd(&cnt[binned[base + j] >> 24], 1);
    }
    __syncthreads();
    int v = 0;
    if (tid < 256) { v = cnt[tid]; loc[tid] = v; }
    __syncthreads();
    for (int off = 1; off < 256; off <<= 1) {
        int t = 0;
        if (tid < 256 && tid >= off) t = loc[tid - off];
        __syncthreads();
        if (tid < 256) loc[tid] += t;
        __syncthreads();
    }
    if (tid < 256) {
        int excl = loc[tid] - v;
        cur[tid] = excl;
        if (tid < nr) {
            row_beg[n0 + tid] = (int)base + excl;
            row_end[n0 + tid] = (int)base + excl + v;
        }
    }
    __syncthreads();
    for (int j = tid; j < tot; j += 1024) {
        unsigned int w = binned[base + j];
        int pos = atomicAdd(&cur[w >> 24], 1);
        csr_src[base + pos] = (int)(w & 0xFFFFFFu);
    }
}

// ---------------------------------------------------------------------------
// K3: layer-1 gather + finalize — the R5/R7-PROVEN body, unchanged.
// ONE WAVE per dst node (block 256 = 4 nodes); 2x32-lane edge-groups;
// half4 (8B dwordx2) h0 loads; redundant-but-overlappable exp per 8-lane
// head group; register accumulators; shfl combine; prefolded pre0/pre1.
// (R6 half8/16-lane, R9 two-phase LDS, R10 LDS-atomic variants all
// regressed — do not restructure this loop.)
// ---------------------------------------------------------------------------
__global__ void gather1_kernel(const int* __restrict__ row_beg,
                               const int* __restrict__ row_end,
                               const int* __restrict__ csr_src,
                               const half4* __restrict__ h0,
                               const float* __restrict__ as1,
                               const float* __restrict__ ad1,
                               const float* __restrict__ pre0,
                               const float* __restrict__ pre1,
                               const float* __restrict__ W2,
                               float* __restrict__ h2, int N) {
    int n = blockIdx.x * 4 + (threadIdx.x >> 6);
    if (n >= N) return;
    int lane = threadIdx.x & 63;
    int sub  = lane & 31;           // half4 index within the 128-ch row
    int grp  = lane >> 5;           // which edge of the pair
    int head = sub >> 3;            // channels 4*sub..4*sub+3 are in this head
    float ad = ad1[(size_t)n * 4 + head];
    int beg = row_beg[n];
    int end = row_end[n];
    float4 acc = make_float4(0.f, 0.f, 0.f, 0.f);
    float den = 0.f;
#pragma unroll 2
    for (int j = beg + grp; j < end; j += 2) {
        int src = csr_src[j];
        float as = as1[(size_t)src * 4 + head];
        float lg = as + ad;
        float l = fmaf(NEG_SLOPE, fminf(lg, 0.f), fmaxf(lg, 0.f));
        float w = __expf(l);
        half4 hv = h0[(size_t)src * 32 + sub];
        acc.x = fmaf(w, (float)hv.x, acc.x);
        acc.y = fmaf(w, (float)hv.y, acc.y);
        acc.z = fmaf(w, (float)hv.z, acc.z);
        acc.w = fmaf(w, (float)hv.w, acc.w);
        den += w;
    }
    acc.x += __shfl_xor(acc.x, 32);
    acc.y += __shfl_xor(acc.y, 32);
    acc.z += __shfl_xor(acc.z, 32);
    acc.w += __shfl_xor(acc.w, 32);
    den   += __shfl_xor(den, 32);
    float inv = 1.f / (den + 1e-16f);
    int c = sub * 4;
    float v0 = fmaf(acc.x * inv, pre0[c],     pre1[c]);
    float v1 = fmaf(acc.y * inv, pre0[c + 1], pre1[c + 1]);
    float v2 = fmaf(acc.z * inv, pre0[c + 2], pre1[c + 2]);
    float v3 = fmaf(acc.w * inv, pre0[c + 3], pre1[c + 3]);
    v0 = v0 > 0.f ? v0 : expm1f(v0);
    v1 = v1 > 0.f ? v1 : expm1f(v1);
    v2 = v2 > 0.f ? v2 : expm1f(v2);
    v3 = v3 > 0.f ? v3 : expm1f(v3);
    float t = v0 * W2[c] + v1 * W2[c + 1] + v2 * W2[c + 2] + v3 * W2[c + 3];
#pragma unroll
    for (int off = 16; off >= 1; off >>= 1) t += __shfl_xor(t, off);
    if (lane == 0) h2[n] = t;
}

// ---------------------------------------------------------------------------
// K4: layer-2 gather (R7-proven). 16-lane group per dst node
// (block 256 = 16 nodes); mean degree ~17 -> lanes ~fully utilized.
// ---------------------------------------------------------------------------
__global__ void gather2_kernel(const int* __restrict__ row_beg,
                               const int* __restrict__ row_end,
                               const int* __restrict__ csr_src,
                               const float* __restrict__ h2,
                               const float* __restrict__ att_s2,
                               const float* __restrict__ att_d2,
                               const float* __restrict__ b2,
                               float* __restrict__ out, int N) {
    int n = blockIdx.x * 16 + (threadIdx.x >> 4);
    if (n >= N) return;
    int lane = threadIdx.x & 15;
    int beg = row_beg[n];
    int end = row_end[n];
    float a_s = att_s2[0];
    float a_d = att_d2[0];
    float hd = h2[n];
    float num = 0.f, den = 0.f;
    for (int j = beg + lane; j < end; j += 16) {
        int src = csr_src[j];
        float hs = h2[src];
        float lg = hs * a_s + hd * a_d;
        float l = fmaf(NEG_SLOPE, fminf(lg, 0.f), fmaxf(lg, 0.f));
        float w = __expf(l);
        num += w * hs;
        den += w;
    }
#pragma unroll
    for (int off = 8; off >= 1; off >>= 1) {
        num += __shfl_xor(num, off);
        den += __shfl_xor(den, off);
    }
    if (lane == 0) out[n] = num / (den + 1e-16f) + b2[0];
}

extern "C" void kernel_launch(void* const* d_in, const int* in_sizes, int n_in,
                              void* d_out, int out_size, void* d_ws, size_t ws_size,
                              hipStream_t stream) {
    const float* x     = (const float*)d_in[0];
    const int*   ei    = (const int*)  d_in[1];
    const float* W1    = (const float*)d_in[2];
    const float* atts1 = (const float*)d_in[3];
    const float* attd1 = (const float*)d_in[4];
    const float* b1    = (const float*)d_in[5];
    const float* W2    = (const float*)d_in[6];
    const float* atts2 = (const float*)d_in[7];
    const float* attd2 = (const float*)d_in[8];
    const float* b2    = (const float*)d_in[9];
    const float* bn_g  = (const float*)d_in[10];
    const float* bn_b  = (const float*)d_in[11];
    const float* bn_m  = (const float*)d_in[12];
    const float* bn_v  = (const float*)d_in[13];

    const int N = in_sizes[0] / 64;     // 100000
    const int E = in_sizes[1] / 2;      // 1600000
    const int T = E + N;
    const int NBK = (N + 255) >> BK_SHIFT;            // 256-node buckets
    const int NCH = (T + CHUNK - 1) / CHUNK;          // binning blocks
    const int NGB = (N + 7) / 8;                      // gemm blocks

    // workspace layout (manual alignment)
    char* p = (char*)d_ws;
    auto alloc = [&](size_t bytes, size_t align) -> void* {
        uintptr_t q = ((uintptr_t)p + align - 1) & ~(uintptr_t)(align - 1);
        p = (char*)(q + bytes);
        return (void*)q;
    };
    _Float16* h0      = (_Float16*)alloc((size_t)N * 128 * 2, 16);
    float* as1        = (float*)alloc((size_t)N * 4 * 4, 16);
    float* ad1        = (float*)alloc((size_t)N * 4 * 4, 16);
    float* h2         = (float*)alloc((size_t)N * 4, 16);
    float* pre0       = (float*)alloc(128 * 4, 16);
    float* pre1       = (float*)alloc(128 * 4, 16);
    int*   row_beg    = (int*)alloc((size_t)N * 4, 16);
    int*   row_end    = (int*)alloc((size_t)N * 4, 16);
    int*   bucket_cur = (int*)alloc((size_t)MAXBK * 4, 16);
    unsigned int* binned = (unsigned int*)alloc((size_t)NBK * CAP * 4, 16);
    int*   csr_src    = (int*)alloc((size_t)NBK * CAP * 4, 16);

    prep_kernel<<<1, 512, 0, stream>>>(b1, bn_g, bn_b, bn_m, bn_v,
                                       pre0, pre1, bucket_cur);

    gemm_bin_kernel<<<NCH + NGB, 256, 0, stream>>>(
        x, W1, atts1, attd1, h0, as1, ad1, N,
        ei, E, NBK, bucket_cur, binned, NCH);

    csr_kernel<<<NBK, 1024, 0, stream>>>(binned, bucket_cur, N,
                                         row_beg, row_end, csr_src);

    gather1_kernel<<<(N + 3) / 4, 256, 0, stream>>>(
        row_beg, row_end, csr_src, (const half4*)h0, as1, ad1, pre0, pre1,
        W2, h2, N);

    gather2_kernel<<<(N + 15) / 16, 256, 0, stream>>>(
        row_beg, row_end, csr_src, h2, atts2, attd2, b2, (float*)d_out, N);
}